// Round 2
// baseline (630.522 us; speedup 1.0000x reference)
//
#include <hip/hip_runtime.h>
#include <stdint.h>

#define B_ 2
#define S_ 2048
#define D_ 2048
#define H_ 16
#define KVH_ 4
#define HD_ 128
#define ROT_ 64
#define WINDOW_ 1024
#define EPS_ 1e-6f
#define M_ (B_ * S_)
#define NQKV_ 3072

typedef unsigned short ushort_t;
typedef float f32x4 __attribute__((ext_vector_type(4)));
typedef short bf16x8 __attribute__((ext_vector_type(8)));

#define NINF (-__builtin_inff())

__device__ __forceinline__ ushort_t f2bf(float f) {
  unsigned int u;
  __builtin_memcpy(&u, &f, 4);
  u += 0x7fff + ((u >> 16) & 1);   // round-to-nearest-even
  return (ushort_t)(u >> 16);
}
__device__ __forceinline__ float bf2f(ushort_t h) {
  unsigned int u = ((unsigned int)h) << 16;
  float f; __builtin_memcpy(&f, &u, 4);
  return f;
}
// split 8 consecutive f32 into hi/lo bf16x8 packs
__device__ __forceinline__ void split8(const float* p, uint4& hi, uint4& lo) {
  float4 a = *reinterpret_cast<const float4*>(p);
  float4 b = *reinterpret_cast<const float4*>(p + 4);
  float v[8] = { a.x, a.y, a.z, a.w, b.x, b.y, b.z, b.w };
  ushort_t h[8], l[8];
#pragma unroll
  for (int i = 0; i < 8; ++i) {
    h[i] = f2bf(v[i]);
    l[i] = f2bf(v[i] - bf2f(h[i]));
  }
  __builtin_memcpy(&hi, h, 16);
  __builtin_memcpy(&lo, l, 16);
}

// ---------------- transpose f32 [R][C] -> split bf16 hi/lo [C][R] ----------------
__launch_bounds__(256, 4)
__global__ void transpose_f32_split(const float* __restrict__ src, ushort_t* __restrict__ dh,
                                    ushort_t* __restrict__ dl, int R, int C) {
  __shared__ float tile[32][33];
  int c0 = blockIdx.x * 32, r0 = blockIdx.y * 32;
  int tx = threadIdx.x & 31, ty = threadIdx.x >> 5;
#pragma unroll
  for (int i = 0; i < 32; i += 8)
    tile[ty + i][tx] = src[(size_t)(r0 + ty + i) * C + c0 + tx];
  __syncthreads();
#pragma unroll
  for (int i = 0; i < 32; i += 8) {
    float v = tile[tx][ty + i];
    ushort_t h = f2bf(v);
    size_t idx = (size_t)(c0 + ty + i) * R + r0 + tx;
    dh[idx] = h;
    dl[idx] = f2bf(v - bf2f(h));
  }
}

// ---------------- batched transpose bf16 [R][C] -> [C][R] ----------------
__launch_bounds__(256, 4)
__global__ void transpose_bf16(const ushort_t* __restrict__ src, ushort_t* __restrict__ dst,
                               int R, int C) {
  __shared__ ushort_t tile[32][33];
  size_t base = (size_t)blockIdx.z * R * C;
  src += base; dst += base;
  int c0 = blockIdx.x * 32, r0 = blockIdx.y * 32;
  int tx = threadIdx.x & 31, ty = threadIdx.x >> 5;
#pragma unroll
  for (int i = 0; i < 32; i += 8)
    tile[ty + i][tx] = src[(size_t)(r0 + ty + i) * C + c0 + tx];
  __syncthreads();
#pragma unroll
  for (int i = 0; i < 32; i += 8)
    dst[(size_t)(c0 + ty + i) * R + r0 + tx] = tile[tx][ty + i];
}

// ---------------- split-precision GEMM: C[M][N] f32 = A[M][K] @ B^T ----------------
// MODE 0: A f32 (split on the fly, 3-term: Ah*Bh + Ah*Bl + Al*Bh)
// MODE 1: A bf16 single (2-term: A*Bh + A*Bl), A has row stride lda (ushorts)
// B pre-split bf16 hi/lo [N][K].
template<int MODE>
__launch_bounds__(256, 2)
__global__ void gemm_split(const float* __restrict__ Af, const ushort_t* __restrict__ Abf,
                           long lda, const ushort_t* __restrict__ Bh,
                           const ushort_t* __restrict__ Bl, float* __restrict__ C,
                           int M, int N, int K) {
  __shared__ __attribute__((aligned(16))) ushort_t Ash[128][40];  // 80B stride (16B mult)
  __shared__ __attribute__((aligned(16))) ushort_t Asl[128][40];
  __shared__ __attribute__((aligned(16))) ushort_t Bsh[128][40];
  __shared__ __attribute__((aligned(16))) ushort_t Bsl[128][40];
  const int bm = blockIdx.y * 128, bn = blockIdx.x * 128;
  const int tid = threadIdx.x;
  const int lane = tid & 63, wid = tid >> 6;
  const int wm = (wid >> 1) * 64, wn = (wid & 1) * 64;
  const int rr = lane & 15, rg = lane >> 4;
  const int sr = tid >> 2, scol = (tid & 3) * 8;
  f32x4 acc[4][4] = {};
  for (int k0 = 0; k0 < K; k0 += 32) {
    uint4 ah0, al0, ah1, al1, bh0, bl0, bh1, bl1;
    if constexpr (MODE == 0) {
      const float* a0 = Af + (size_t)(bm + sr) * lda + k0 + scol;
      split8(a0, ah0, al0);
      split8(a0 + (size_t)64 * lda, ah1, al1);
    } else {
      ah0 = *reinterpret_cast<const uint4*>(Abf + (size_t)(bm + sr) * lda + k0 + scol);
      ah1 = *reinterpret_cast<const uint4*>(Abf + (size_t)(bm + sr + 64) * lda + k0 + scol);
    }
    bh0 = *reinterpret_cast<const uint4*>(Bh + (size_t)(bn + sr) * K + k0 + scol);
    bh1 = *reinterpret_cast<const uint4*>(Bh + (size_t)(bn + sr + 64) * K + k0 + scol);
    bl0 = *reinterpret_cast<const uint4*>(Bl + (size_t)(bn + sr) * K + k0 + scol);
    bl1 = *reinterpret_cast<const uint4*>(Bl + (size_t)(bn + sr + 64) * K + k0 + scol);
    __syncthreads();   // previous tile fully consumed
    *reinterpret_cast<uint4*>(&Ash[sr][scol])      = ah0;
    *reinterpret_cast<uint4*>(&Ash[sr + 64][scol]) = ah1;
    if constexpr (MODE == 0) {
      *reinterpret_cast<uint4*>(&Asl[sr][scol])      = al0;
      *reinterpret_cast<uint4*>(&Asl[sr + 64][scol]) = al1;
    }
    *reinterpret_cast<uint4*>(&Bsh[sr][scol])      = bh0;
    *reinterpret_cast<uint4*>(&Bsh[sr + 64][scol]) = bh1;
    *reinterpret_cast<uint4*>(&Bsl[sr][scol])      = bl0;
    *reinterpret_cast<uint4*>(&Bsl[sr + 64][scol]) = bl1;
    __syncthreads();
    bf16x8 ah[4], al[4], bhf[4], blf[4];
#pragma unroll
    for (int i = 0; i < 4; ++i) {
      ah[i]  = *reinterpret_cast<const bf16x8*>(&Ash[wm + i * 16 + rr][rg * 8]);
      bhf[i] = *reinterpret_cast<const bf16x8*>(&Bsh[wn + i * 16 + rr][rg * 8]);
      blf[i] = *reinterpret_cast<const bf16x8*>(&Bsl[wn + i * 16 + rr][rg * 8]);
      if constexpr (MODE == 0)
        al[i] = *reinterpret_cast<const bf16x8*>(&Asl[wm + i * 16 + rr][rg * 8]);
    }
#pragma unroll
    for (int i = 0; i < 4; ++i)
#pragma unroll
      for (int j = 0; j < 4; ++j) {
        acc[i][j] = __builtin_amdgcn_mfma_f32_16x16x32_bf16(ah[i], bhf[j], acc[i][j], 0, 0, 0);
        acc[i][j] = __builtin_amdgcn_mfma_f32_16x16x32_bf16(ah[i], blf[j], acc[i][j], 0, 0, 0);
        if constexpr (MODE == 0)
          acc[i][j] = __builtin_amdgcn_mfma_f32_16x16x32_bf16(al[i], bhf[j], acc[i][j], 0, 0, 0);
      }
  }
#pragma unroll
  for (int i = 0; i < 4; ++i)
#pragma unroll
    for (int j = 0; j < 4; ++j)
#pragma unroll
      for (int r = 0; r < 4; ++r)
        C[(size_t)(bm + wm + i * 16 + rg * 4 + r) * N + (bn + wn + j * 16 + rr)] = acc[i][j][r];
}

// ---------------- RMSNorm + RoPE for K (split bf16 out) and V (single bf16) ----------
// one wave per 128-dim chunk; 8 chunks/row: c<4 -> k head c, else v head c-4
__launch_bounds__(256, 4)
__global__ void norm_rope_kv(const float* __restrict__ qkv, const float* __restrict__ cosb,
                             const float* __restrict__ sinb, const float* __restrict__ ksc,
                             ushort_t* __restrict__ kh, ushort_t* __restrict__ kl,
                             ushort_t* __restrict__ vb) {
  int gw = blockIdx.x * 4 + (threadIdx.x >> 6);
  int lane = threadIdx.x & 63;
  int row = gw >> 3, c = gw & 7;
  int b = row >> 11, s = row & (S_ - 1);
  int col = (c < 4) ? (2048 + c * 128) : (2560 + (c - 4) * 128);
  const float* src = qkv + (size_t)row * NQKV_ + col;
  float2 v = *reinterpret_cast<const float2*>(src + lane * 2);
  float ss = v.x * v.x + v.y * v.y;
#pragma unroll
  for (int off = 32; off; off >>= 1) ss += __shfl_xor(ss, off);
  float inv = rsqrtf(ss * (1.0f / HD_) + EPS_);
  float x0 = v.x * inv, x1 = v.y * inv;
  int d0 = lane * 2;
  if (c < 4) {  // k: (1+scale) then rope on dims [0,64)
    x0 *= (1.0f + ksc[d0]);
    x1 *= (1.0f + ksc[d0 + 1]);
    float y0 = __shfl_xor(x0, 16);
    float y1 = __shfl_xor(x1, 16);
    if (d0 < ROT_) {
      int dm = d0 & 31;
      float cs0 = cosb[s * 32 + dm],     sn0 = sinb[s * 32 + dm];
      float cs1 = cosb[s * 32 + dm + 1], sn1 = sinb[s * 32 + dm + 1];
      if (d0 < 32) { x0 = x0 * cs0 - y0 * sn0; x1 = x1 * cs1 - y1 * sn1; }
      else         { x0 = x0 * cs0 + y0 * sn0; x1 = x1 * cs1 + y1 * sn1; }
    }
    size_t idx = ((size_t)((b * KVH_ + c) * S_ + s)) * HD_ + d0;
    ushort_t h0 = f2bf(x0), h1 = f2bf(x1);
    ushort_t l0 = f2bf(x0 - bf2f(h0)), l1 = f2bf(x1 - bf2f(h1));
    ushort_t ph[2] = { h0, h1 }, pl[2] = { l0, l1 };
    unsigned int wh, wl;
    __builtin_memcpy(&wh, ph, 4); __builtin_memcpy(&wl, pl, 4);
    *reinterpret_cast<unsigned int*>(kh + idx) = wh;
    *reinterpret_cast<unsigned int*>(kl + idx) = wl;
  } else {      // v: plain rmsnorm, single bf16
    size_t idx = ((size_t)((b * KVH_ + (c - 4)) * S_ + s)) * HD_ + d0;
    ushort_t o[2] = { f2bf(x0), f2bf(x1) };
    unsigned int pk; __builtin_memcpy(&pk, o, 4);
    *reinterpret_cast<unsigned int*>(vb + idx) = pk;
  }
}

// ---------------- flash attention, sliding window, GQA ----------------
// grid (S/64, H, B); 4 waves/block, each wave owns 16 q rows. KV tiles of 32 keys.
// Q: read f32 from qkv buffer, rmsnorm+rope+split IN KERNEL (f32-accurate logits).
// K: pre-split bf16 hi/lo; QK^T = qh*kh + qh*kl + ql*kh. V transposed [HD][S] bf16.
// ctx out: bf16 written strided into the dead k/v-part of qkv (row stride 6144 ushorts).
__launch_bounds__(256, 2)
__global__ void flash_attn(const float* __restrict__ qkv, const float* __restrict__ cosb,
                           const float* __restrict__ sinb, const float* __restrict__ qsc,
                           const ushort_t* __restrict__ khb, const ushort_t* __restrict__ klb,
                           const ushort_t* __restrict__ vt, ushort_t* __restrict__ ctxh) {
  const int qtile = blockIdx.x, h = blockIdx.y, b = blockIdx.z;
  const int kvh = h >> 2;
  const int lane = threadIdx.x & 63, w = threadIdx.x >> 6;
  const int rr = lane & 15, rg = lane >> 4;
  const int qBase = qtile * 64;
  const int qw = qBase + w * 16;
  const int srow = qw + rr;
  // ---- in-register q: load f32, rmsnorm, scale, rope, split ----
  const float* qrow = qkv + (size_t)(b * S_ + srow) * NQKV_ + h * HD_;
  float qv[4][8];
  float ssq = 0.f;
#pragma unroll
  for (int kk = 0; kk < 4; ++kk) {
    float4 u0 = *reinterpret_cast<const float4*>(qrow + kk * 32 + rg * 8);
    float4 u1 = *reinterpret_cast<const float4*>(qrow + kk * 32 + rg * 8 + 4);
    qv[kk][0] = u0.x; qv[kk][1] = u0.y; qv[kk][2] = u0.z; qv[kk][3] = u0.w;
    qv[kk][4] = u1.x; qv[kk][5] = u1.y; qv[kk][6] = u1.z; qv[kk][7] = u1.w;
#pragma unroll
    for (int j = 0; j < 8; ++j) ssq += qv[kk][j] * qv[kk][j];
  }
  ssq += __shfl_xor(ssq, 16);
  ssq += __shfl_xor(ssq, 32);
  float inv = rsqrtf(ssq * (1.0f / HD_) + EPS_);
#pragma unroll
  for (int kk = 0; kk < 4; ++kk)
#pragma unroll
    for (int j = 0; j < 8; ++j)
      qv[kk][j] *= inv * (1.0f + qsc[kk * 32 + rg * 8 + j]);
  {
    const float* cs = cosb + (size_t)srow * 32;
    const float* sn = sinb + (size_t)srow * 32;
#pragma unroll
    for (int j = 0; j < 8; ++j) {
      int d = rg * 8 + j;
      float c = cs[d], s = sn[d];
      float x0 = qv[0][j], x1 = qv[1][j];
      qv[0][j] = x0 * c - x1 * s;
      qv[1][j] = x1 * c + x0 * s;
    }
  }
  bf16x8 qfh[4], qfl[4];
#pragma unroll
  for (int kk = 0; kk < 4; ++kk)
#pragma unroll
    for (int j = 0; j < 8; ++j) {
      ushort_t hh = f2bf(qv[kk][j]);
      qfh[kk][j] = (short)hh;
      qfl[kk][j] = (short)f2bf(qv[kk][j] - bf2f(hh));
    }
  // ---- KV loop ----
  const ushort_t* KH = khb + (size_t)(b * KVH_ + kvh) * S_ * HD_;
  const ushort_t* KL = klb + (size_t)(b * KVH_ + kvh) * S_ * HD_;
  const ushort_t* V  = vt  + (size_t)(b * KVH_ + kvh) * HD_ * S_;
  f32x4 acc[8] = {};
  float m_run[4], l_run[4];
#pragma unroll
  for (int r = 0; r < 4; ++r) { m_run[r] = NINF; l_run[r] = 0.f; }
  __shared__ __attribute__((aligned(16))) ushort_t Pb[4][16][40];  // per-wave P buffer
  int kvStart = qBase - (WINDOW_ - 1);
  if (kvStart < 0) kvStart = 0;
  kvStart &= ~31;
  const int kvEnd = qBase + 63;
  for (int key0 = kvStart; key0 <= kvEnd; key0 += 32) {
    f32x4 sc[2];
#pragma unroll
    for (int nt = 0; nt < 2; ++nt) {
      f32x4 s = {};
#pragma unroll
      for (int kk = 0; kk < 4; ++kk) {
        size_t koff = (size_t)(key0 + nt * 16 + rr) * HD_ + kk * 32 + rg * 8;
        bf16x8 kfh = *reinterpret_cast<const bf16x8*>(KH + koff);
        bf16x8 kfl = *reinterpret_cast<const bf16x8*>(KL + koff);
        s = __builtin_amdgcn_mfma_f32_16x16x32_bf16(qfh[kk], kfh, s, 0, 0, 0);
        s = __builtin_amdgcn_mfma_f32_16x16x32_bf16(qfh[kk], kfl, s, 0, 0, 0);
        s = __builtin_amdgcn_mfma_f32_16x16x32_bf16(qfl[kk], kfh, s, 0, 0, 0);
      }
      sc[nt] = s;
    }
    // mask + row max (rows: rg*4+r, cols: key0 + nt*16 + rr)
    float tmax[4] = { NINF, NINF, NINF, NINF };
#pragma unroll
    for (int nt = 0; nt < 2; ++nt)
#pragma unroll
      for (int r = 0; r < 4; ++r) {
        int qi = qw + rg * 4 + r;
        int kj = key0 + nt * 16 + rr;
        bool valid = (kj <= qi) && (qi - kj < WINDOW_);
        float sv = valid ? sc[nt][r] : NINF;
        sc[nt][r] = sv;
        tmax[r] = fmaxf(tmax[r], sv);
      }
#pragma unroll
    for (int off = 1; off < 16; off <<= 1)
#pragma unroll
      for (int r = 0; r < 4; ++r)
        tmax[r] = fmaxf(tmax[r], __shfl_xor(tmax[r], off));
    float alpha[4];
#pragma unroll
    for (int r = 0; r < 4; ++r) {
      float mn = fmaxf(m_run[r], tmax[r]);
      alpha[r] = (mn == NINF) ? 1.0f : __expf(m_run[r] - mn);
      m_run[r] = mn;
    }
    float psum[4] = { 0.f, 0.f, 0.f, 0.f };
#pragma unroll
    for (int nt = 0; nt < 2; ++nt)
#pragma unroll
      for (int r = 0; r < 4; ++r) {
        float sv = sc[nt][r];
        float p = (sv == NINF) ? 0.f : __expf(sv - m_run[r]);
        sc[nt][r] = p;
        psum[r] += p;
      }
#pragma unroll
    for (int off = 1; off < 16; off <<= 1)
#pragma unroll
      for (int r = 0; r < 4; ++r)
        psum[r] += __shfl_xor(psum[r], off);
#pragma unroll
    for (int r = 0; r < 4; ++r) l_run[r] = l_run[r] * alpha[r] + psum[r];
#pragma unroll
    for (int n = 0; n < 8; ++n)
#pragma unroll
      for (int r = 0; r < 4; ++r) acc[n][r] *= alpha[r];
    // P -> per-wave LDS (C-layout) then read back as A-fragment (no block barrier needed)
#pragma unroll
    for (int nt = 0; nt < 2; ++nt)
#pragma unroll
      for (int r = 0; r < 4; ++r)
        Pb[w][rg * 4 + r][nt * 16 + rr] = f2bf(sc[nt][r]);
    bf16x8 pf = *reinterpret_cast<const bf16x8*>(&Pb[w][rr][rg * 8]);
#pragma unroll
    for (int n = 0; n < 8; ++n) {
      bf16x8 vf = *reinterpret_cast<const bf16x8*>(
          V + (size_t)(n * 16 + rr) * S_ + key0 + rg * 8);
      acc[n] = __builtin_amdgcn_mfma_f32_16x16x32_bf16(pf, vf, acc[n], 0, 0, 0);
    }
  }
  // epilogue: normalize, write ctx (bf16) strided into qkv k/v-part: row stride 6144
#pragma unroll
  for (int n = 0; n < 8; ++n)
#pragma unroll
    for (int r = 0; r < 4; ++r) {
      float o = acc[n][r] / l_run[r];
      int qi = qw + rg * 4 + r;
      ctxh[(size_t)(b * S_ + qi) * 6144 + h * HD_ + n * 16 + rr] = f2bf(o);
    }
}

extern "C" void kernel_launch(void* const* d_in, const int* in_sizes, int n_in,
                              void* d_out, int out_size, void* d_ws, size_t ws_size,
                              hipStream_t stream) {
  const float* x    = (const float*)d_in[0];
  // d_in[1] = mask (recomputed analytically)
  const float* cosb = (const float*)d_in[2];
  const float* sinb = (const float*)d_in[3];
  const float* Wq   = (const float*)d_in[4];
  const float* Wk   = (const float*)d_in[5];
  const float* Wv   = (const float*)d_in[6];
  const float* Wo   = (const float*)d_in[7];
  const float* qsc  = (const float*)d_in[8];
  const float* ksc  = (const float*)d_in[9];
  float* out = (float*)d_out;

  char* ws = (char*)d_ws;
  const size_t MB = 1ull << 20;
  // [0,12)   wqkvT_h  -> after QKV gemm reused: kh[0,4) kl[4,8) vb[8,12)
  // [12,24)  wqkvT_l  -> reused: vtb[12,16)
  // [24,32)  woT_h ; [32,40) woT_l
  // [40,88)  qkv f32 (ctx bf16 lives strided in its k/v-part after norm_rope)
  ushort_t* wqkvT_h = (ushort_t*)(ws + 0 * MB);
  ushort_t* wqkvT_l = (ushort_t*)(ws + 12 * MB);
  ushort_t* kh      = (ushort_t*)(ws + 0 * MB);
  ushort_t* kl      = (ushort_t*)(ws + 4 * MB);
  ushort_t* vb      = (ushort_t*)(ws + 8 * MB);
  ushort_t* vtb     = (ushort_t*)(ws + 12 * MB);
  ushort_t* woT_h   = (ushort_t*)(ws + 24 * MB);
  ushort_t* woT_l   = (ushort_t*)(ws + 32 * MB);
  float*    qkv     = (float*)(ws + 40 * MB);
  ushort_t* ctxh    = (ushort_t*)qkv + 4096;  // strided: row i at i*6144 + [0,2048)

  transpose_f32_split<<<dim3(64, 64), 256, 0, stream>>>(Wq, wqkvT_h, wqkvT_l, D_, 2048);
  transpose_f32_split<<<dim3(16, 64), 256, 0, stream>>>(Wk, wqkvT_h + (size_t)2048 * D_,
                                                        wqkvT_l + (size_t)2048 * D_, D_, 512);
  transpose_f32_split<<<dim3(16, 64), 256, 0, stream>>>(Wv, wqkvT_h + (size_t)2560 * D_,
                                                        wqkvT_l + (size_t)2560 * D_, D_, 512);
  transpose_f32_split<<<dim3(64, 64), 256, 0, stream>>>(Wo, woT_h, woT_l, D_, D_);
  gemm_split<0><<<dim3(NQKV_ / 128, M_ / 128), 256, 0, stream>>>(
      x, nullptr, (long)D_, wqkvT_h, wqkvT_l, qkv, M_, NQKV_, D_);
  norm_rope_kv<<<dim3(M_ * 8 / 4), 256, 0, stream>>>(qkv, cosb, sinb, ksc, kh, kl, vb);
  transpose_bf16<<<dim3(HD_ / 32, S_ / 32, B_ * KVH_), 256, 0, stream>>>(vb, vtb, S_, HD_);
  flash_attn<<<dim3(S_ / 64, H_, B_), 256, 0, stream>>>(qkv, cosb, sinb, qsc, kh, kl, vtb, ctxh);
  gemm_split<1><<<dim3(D_ / 128, M_ / 128), 256, 0, stream>>>(
      nullptr, ctxh, 6144, woT_h, woT_l, out, M_, D_, D_);
}

// Round 3
// 397.219 us; speedup vs baseline: 1.5873x; 1.5873x over previous
//
#include <hip/hip_runtime.h>
#include <stdint.h>

#define B_ 2
#define S_ 2048
#define D_ 2048
#define H_ 16
#define KVH_ 4
#define HD_ 128
#define ROT_ 64
#define WINDOW_ 1024
#define EPS_ 1e-6f
#define M_ (B_ * S_)
#define NQKV_ 3072

#define QBLK 256
#define KVBLK 32

typedef unsigned short ushort_t;
typedef _Float16 f16;
typedef float f32x4 __attribute__((ext_vector_type(4)));
typedef short bf16x8 __attribute__((ext_vector_type(8)));
typedef f16 f16x8 __attribute__((ext_vector_type(8)));

#define NINF (-__builtin_inff())

__device__ __forceinline__ ushort_t f2bf(float f) {
  unsigned int u;
  __builtin_memcpy(&u, &f, 4);
  u += 0x7fff + ((u >> 16) & 1);   // round-to-nearest-even
  return (ushort_t)(u >> 16);
}
__device__ __forceinline__ float bf2f(ushort_t h) {
  unsigned int u = ((unsigned int)h) << 16;
  float f; __builtin_memcpy(&f, &u, 4);
  return f;
}
// split 8 consecutive f32 into hi/lo bf16x8 packs
__device__ __forceinline__ void split8(const float* p, uint4& hi, uint4& lo) {
  float4 a = *reinterpret_cast<const float4*>(p);
  float4 b = *reinterpret_cast<const float4*>(p + 4);
  float v[8] = { a.x, a.y, a.z, a.w, b.x, b.y, b.z, b.w };
  ushort_t h[8], l[8];
#pragma unroll
  for (int i = 0; i < 8; ++i) {
    h[i] = f2bf(v[i]);
    l[i] = f2bf(v[i] - bf2f(h[i]));
  }
  __builtin_memcpy(&hi, h, 16);
  __builtin_memcpy(&lo, l, 16);
}

// async global->LDS, 16B per lane. dst must be wave-uniform; HW adds lane*16.
__device__ __forceinline__ void gload16(const void* g, void* l) {
  __builtin_amdgcn_global_load_lds(
      (const __attribute__((address_space(1))) void*)g,
      (__attribute__((address_space(3))) void*)l, 16, 0, 0);
}

// ---------------- transpose f32 [R][C] -> split bf16 hi/lo [C][R] ----------------
__launch_bounds__(256, 4)
__global__ void transpose_f32_split(const float* __restrict__ src, ushort_t* __restrict__ dh,
                                    ushort_t* __restrict__ dl, int R, int C) {
  __shared__ float tile[32][33];
  int c0 = blockIdx.x * 32, r0 = blockIdx.y * 32;
  int tx = threadIdx.x & 31, ty = threadIdx.x >> 5;
#pragma unroll
  for (int i = 0; i < 32; i += 8)
    tile[ty + i][tx] = src[(size_t)(r0 + ty + i) * C + c0 + tx];
  __syncthreads();
#pragma unroll
  for (int i = 0; i < 32; i += 8) {
    float v = tile[tx][ty + i];
    ushort_t h = f2bf(v);
    size_t idx = (size_t)(c0 + ty + i) * R + r0 + tx;
    dh[idx] = h;
    dl[idx] = f2bf(v - bf2f(h));
  }
}

// ---------------- batched transpose 16-bit [R][C] -> [C][R] ----------------
__launch_bounds__(256, 4)
__global__ void transpose_bf16(const ushort_t* __restrict__ src, ushort_t* __restrict__ dst,
                               int R, int C) {
  __shared__ ushort_t tile[32][33];
  size_t base = (size_t)blockIdx.z * R * C;
  src += base; dst += base;
  int c0 = blockIdx.x * 32, r0 = blockIdx.y * 32;
  int tx = threadIdx.x & 31, ty = threadIdx.x >> 5;
#pragma unroll
  for (int i = 0; i < 32; i += 8)
    tile[ty + i][tx] = src[(size_t)(r0 + ty + i) * C + c0 + tx];
  __syncthreads();
#pragma unroll
  for (int i = 0; i < 32; i += 8)
    dst[(size_t)(c0 + ty + i) * R + r0 + tx] = tile[tx][ty + i];
}

// ---------------- split-precision GEMM: C[M][N] f32 = A[M][K] @ B^T ----------------
// MODE 0: A f32 (split on the fly, 3-term). MODE 1: A bf16 single (2-term), stride lda.
template<int MODE>
__launch_bounds__(256, 2)
__global__ void gemm_split(const float* __restrict__ Af, const ushort_t* __restrict__ Abf,
                           long lda, const ushort_t* __restrict__ Bh,
                           const ushort_t* __restrict__ Bl, float* __restrict__ C,
                           int M, int N, int K) {
  __shared__ __attribute__((aligned(16))) ushort_t Ash[128][40];
  __shared__ __attribute__((aligned(16))) ushort_t Asl[128][40];
  __shared__ __attribute__((aligned(16))) ushort_t Bsh[128][40];
  __shared__ __attribute__((aligned(16))) ushort_t Bsl[128][40];
  const int bm = blockIdx.y * 128, bn = blockIdx.x * 128;
  const int tid = threadIdx.x;
  const int lane = tid & 63, wid = tid >> 6;
  const int wm = (wid >> 1) * 64, wn = (wid & 1) * 64;
  const int rr = lane & 15, rg = lane >> 4;
  const int sr = tid >> 2, scol = (tid & 3) * 8;
  f32x4 acc[4][4] = {};
  for (int k0 = 0; k0 < K; k0 += 32) {
    uint4 ah0, al0, ah1, al1, bh0, bl0, bh1, bl1;
    if constexpr (MODE == 0) {
      const float* a0 = Af + (size_t)(bm + sr) * lda + k0 + scol;
      split8(a0, ah0, al0);
      split8(a0 + (size_t)64 * lda, ah1, al1);
    } else {
      ah0 = *reinterpret_cast<const uint4*>(Abf + (size_t)(bm + sr) * lda + k0 + scol);
      ah1 = *reinterpret_cast<const uint4*>(Abf + (size_t)(bm + sr + 64) * lda + k0 + scol);
    }
    bh0 = *reinterpret_cast<const uint4*>(Bh + (size_t)(bn + sr) * K + k0 + scol);
    bh1 = *reinterpret_cast<const uint4*>(Bh + (size_t)(bn + sr + 64) * K + k0 + scol);
    bl0 = *reinterpret_cast<const uint4*>(Bl + (size_t)(bn + sr) * K + k0 + scol);
    bl1 = *reinterpret_cast<const uint4*>(Bl + (size_t)(bn + sr + 64) * K + k0 + scol);
    __syncthreads();
    *reinterpret_cast<uint4*>(&Ash[sr][scol])      = ah0;
    *reinterpret_cast<uint4*>(&Ash[sr + 64][scol]) = ah1;
    if constexpr (MODE == 0) {
      *reinterpret_cast<uint4*>(&Asl[sr][scol])      = al0;
      *reinterpret_cast<uint4*>(&Asl[sr + 64][scol]) = al1;
    }
    *reinterpret_cast<uint4*>(&Bsh[sr][scol])      = bh0;
    *reinterpret_cast<uint4*>(&Bsh[sr + 64][scol]) = bh1;
    *reinterpret_cast<uint4*>(&Bsl[sr][scol])      = bl0;
    *reinterpret_cast<uint4*>(&Bsl[sr + 64][scol]) = bl1;
    __syncthreads();
    bf16x8 ah[4], al[4], bhf[4], blf[4];
#pragma unroll
    for (int i = 0; i < 4; ++i) {
      ah[i]  = *reinterpret_cast<const bf16x8*>(&Ash[wm + i * 16 + rr][rg * 8]);
      bhf[i] = *reinterpret_cast<const bf16x8*>(&Bsh[wn + i * 16 + rr][rg * 8]);
      blf[i] = *reinterpret_cast<const bf16x8*>(&Bsl[wn + i * 16 + rr][rg * 8]);
      if constexpr (MODE == 0)
        al[i] = *reinterpret_cast<const bf16x8*>(&Asl[wm + i * 16 + rr][rg * 8]);
    }
#pragma unroll
    for (int i = 0; i < 4; ++i)
#pragma unroll
      for (int j = 0; j < 4; ++j) {
        acc[i][j] = __builtin_amdgcn_mfma_f32_16x16x32_bf16(ah[i], bhf[j], acc[i][j], 0, 0, 0);
        acc[i][j] = __builtin_amdgcn_mfma_f32_16x16x32_bf16(ah[i], blf[j], acc[i][j], 0, 0, 0);
        if constexpr (MODE == 0)
          acc[i][j] = __builtin_amdgcn_mfma_f32_16x16x32_bf16(al[i], bhf[j], acc[i][j], 0, 0, 0);
      }
  }
#pragma unroll
  for (int i = 0; i < 4; ++i)
#pragma unroll
    for (int j = 0; j < 4; ++j)
#pragma unroll
      for (int r = 0; r < 4; ++r)
        C[(size_t)(bm + wm + i * 16 + rg * 4 + r) * N + (bn + wn + j * 16 + rr)] = acc[i][j][r];
}

// ---------------- RMSNorm + RoPE for K and V, fp16 out ----------------
__launch_bounds__(256, 4)
__global__ void norm_rope_kv(const float* __restrict__ qkv, const float* __restrict__ cosb,
                             const float* __restrict__ sinb, const float* __restrict__ ksc,
                             f16* __restrict__ kf, f16* __restrict__ vb) {
  int gw = blockIdx.x * 4 + (threadIdx.x >> 6);
  int lane = threadIdx.x & 63;
  int row = gw >> 3, c = gw & 7;
  int b = row >> 11, s = row & (S_ - 1);
  int col = (c < 4) ? (2048 + c * 128) : (2560 + (c - 4) * 128);
  const float* src = qkv + (size_t)row * NQKV_ + col;
  float2 v = *reinterpret_cast<const float2*>(src + lane * 2);
  float ss = v.x * v.x + v.y * v.y;
#pragma unroll
  for (int off = 32; off; off >>= 1) ss += __shfl_xor(ss, off);
  float inv = rsqrtf(ss * (1.0f / HD_) + EPS_);
  float x0 = v.x * inv, x1 = v.y * inv;
  int d0 = lane * 2;
  f16* dst;
  size_t idx;
  if (c < 4) {  // k: (1+scale) then rope on dims [0,64)
    x0 *= (1.0f + ksc[d0]);
    x1 *= (1.0f + ksc[d0 + 1]);
    float y0 = __shfl_xor(x0, 16);
    float y1 = __shfl_xor(x1, 16);
    if (d0 < ROT_) {
      int dm = d0 & 31;
      float cs0 = cosb[s * 32 + dm],     sn0 = sinb[s * 32 + dm];
      float cs1 = cosb[s * 32 + dm + 1], sn1 = sinb[s * 32 + dm + 1];
      if (d0 < 32) { x0 = x0 * cs0 - y0 * sn0; x1 = x1 * cs1 - y1 * sn1; }
      else         { x0 = x0 * cs0 + y0 * sn0; x1 = x1 * cs1 + y1 * sn1; }
    }
    dst = kf; idx = ((size_t)((b * KVH_ + c) * S_ + s)) * HD_ + d0;
  } else {      // v: plain rmsnorm
    dst = vb; idx = ((size_t)((b * KVH_ + (c - 4)) * S_ + s)) * HD_ + d0;
  }
  f16 o[2] = { (f16)x0, (f16)x1 };
  unsigned int pk; __builtin_memcpy(&pk, o, 4);
  *reinterpret_cast<unsigned int*>(dst + idx) = pk;
}

// ---------------- flash attention v3: fp16 QK/PV, LDS-staged KV, double-buffered ----
// grid (S/256, H, B), 512 threads (8 waves), wave owns 32 q rows (2 rb of 16).
// K fp16 [S][128] staged to LDS swizzled ^((row&7)<<4); V^T fp16 [128][S] staged
// swizzled ^((d&3)<<4); both via global_load_lds w16 (linear dest, inv-swz source).
__launch_bounds__(512, 2)
__global__ void flash_attn(const float* __restrict__ qkv, const float* __restrict__ cosb,
                           const float* __restrict__ sinb, const float* __restrict__ qsc,
                           const f16* __restrict__ kfp, const f16* __restrict__ vt,
                           ushort_t* __restrict__ ctxh) {
  __shared__ __attribute__((aligned(16))) f16 Ks[2][KVBLK][128];
  __shared__ __attribute__((aligned(16))) f16 Vs[2][128][KVBLK];
  __shared__ __attribute__((aligned(16))) f16 Pb[8][32][40];
  const int qtile = blockIdx.x, h = blockIdx.y, b = blockIdx.z;
  const int kvh = h >> 2;
  const int tid = threadIdx.x;
  const int lane = tid & 63, w = tid >> 6;
  const int rr = lane & 15, rg = lane >> 4;
  const int qBase = qtile * QBLK;
  const int qw = qBase + w * 32;
  const f16* Kh = kfp + (size_t)(b * KVH_ + kvh) * S_ * HD_;
  const f16* Vh = vt  + (size_t)(b * KVH_ + kvh) * HD_ * S_;

  // ---- q: load f32, rmsnorm, scale, rope, cvt fp16 (2 row-blocks) ----
  f16x8 qf[2][4];
#pragma unroll
  for (int rb = 0; rb < 2; ++rb) {
    const int srow = qw + rb * 16 + rr;
    const float* qrow = qkv + (size_t)(b * S_ + srow) * NQKV_ + h * HD_;
    float qv[4][8];
    float ssq = 0.f;
#pragma unroll
    for (int kk = 0; kk < 4; ++kk) {
      float4 u0 = *reinterpret_cast<const float4*>(qrow + kk * 32 + rg * 8);
      float4 u1 = *reinterpret_cast<const float4*>(qrow + kk * 32 + rg * 8 + 4);
      qv[kk][0] = u0.x; qv[kk][1] = u0.y; qv[kk][2] = u0.z; qv[kk][3] = u0.w;
      qv[kk][4] = u1.x; qv[kk][5] = u1.y; qv[kk][6] = u1.z; qv[kk][7] = u1.w;
#pragma unroll
      for (int j = 0; j < 8; ++j) ssq += qv[kk][j] * qv[kk][j];
    }
    ssq += __shfl_xor(ssq, 16);
    ssq += __shfl_xor(ssq, 32);
    float inv = rsqrtf(ssq * (1.0f / HD_) + EPS_);
#pragma unroll
    for (int kk = 0; kk < 4; ++kk)
#pragma unroll
      for (int j = 0; j < 8; ++j)
        qv[kk][j] *= inv * (1.0f + qsc[kk * 32 + rg * 8 + j]);
    {
      const float* cs = cosb + (size_t)srow * 32;
      const float* sn = sinb + (size_t)srow * 32;
#pragma unroll
      for (int j = 0; j < 8; ++j) {
        int d = rg * 8 + j;
        float c = cs[d], s = sn[d];
        float x0 = qv[0][j], x1 = qv[1][j];
        qv[0][j] = x0 * c - x1 * s;
        qv[1][j] = x1 * c + x0 * s;
      }
    }
#pragma unroll
    for (int kk = 0; kk < 4; ++kk)
#pragma unroll
      for (int j = 0; j < 8; ++j)
        qf[rb][kk][j] = (f16)qv[kk][j];
  }

  f32x4 acc[2][8] = {};
  float m_run[2][4], l_run[2][4];
#pragma unroll
  for (int rb = 0; rb < 2; ++rb)
#pragma unroll
    for (int r = 0; r < 4; ++r) { m_run[rb][r] = NINF; l_run[rb][r] = 0.f; }

  int kvStart = qBase - (WINDOW_ - 1);
  if (kvStart < 0) kvStart = 0;
  kvStart &= ~(KVBLK - 1);
  const int ntile = (qBase + QBLK - kvStart) / KVBLK;

  // stage K rows rt = w*4 + lane/16, 16B chunk (lane&15); V rows d = w*16 + lane/4.
  const int k_rt = w * 4 + (lane >> 4);
  const int k_cb = (lane & 15) * 16;
  const int k_src_off = (k_cb ^ ((k_rt & 7) << 4));
  const int v_d = w * 16 + (lane >> 2);
  const int v_cb = (lane & 3) * 16;
  const size_t v_src_base = (size_t)v_d * (S_ * 2) + (v_cb ^ ((v_d & 3) << 4));

#define STAGE(bufs, key0)                                                            \
  do {                                                                               \
    gload16((const char*)Kh + (size_t)((key0) + k_rt) * 256 + k_src_off,             \
            (f16*)&Ks[bufs][0][0] + w * 512);                                        \
    gload16((const char*)Vh + v_src_base + (size_t)(key0) * 2,                       \
            (f16*)&Vs[bufs][0][0] + w * 512);                                        \
  } while (0)

  STAGE(0, kvStart);
  __syncthreads();

  for (int t = 0; t < ntile; ++t) {
    const int key0 = kvStart + t * KVBLK;
    const int bufs = t & 1;
    if (t + 1 < ntile) STAGE(bufs ^ 1, key0 + KVBLK);

    // K fragments (shared across both row-blocks)
    f16x8 kfr[2][4];
#pragma unroll
    for (int nt = 0; nt < 2; ++nt)
#pragma unroll
      for (int kk = 0; kk < 4; ++kk) {
        int rt = nt * 16 + rr;
        kfr[nt][kk] = *reinterpret_cast<const f16x8*>(
            (const char*)&Ks[bufs][0][0] + rt * 256 + ((kk * 64 + rg * 16) ^ ((rt & 7) << 4)));
      }

#pragma unroll
    for (int rb = 0; rb < 2; ++rb) {
      f32x4 sc[2];
#pragma unroll
      for (int nt = 0; nt < 2; ++nt) {
        f32x4 s = {};
#pragma unroll
        for (int kk = 0; kk < 4; ++kk)
          s = __builtin_amdgcn_mfma_f32_16x16x32_f16(qf[rb][kk], kfr[nt][kk], s, 0, 0, 0);
        sc[nt] = s;
      }
      float tmax[4] = { NINF, NINF, NINF, NINF };
#pragma unroll
      for (int nt = 0; nt < 2; ++nt)
#pragma unroll
        for (int r = 0; r < 4; ++r) {
          int qi = qw + rb * 16 + rg * 4 + r;
          int kj = key0 + nt * 16 + rr;
          bool valid = (kj <= qi) && (qi - kj < WINDOW_);
          float sv = valid ? sc[nt][r] : NINF;
          sc[nt][r] = sv;
          tmax[r] = fmaxf(tmax[r], sv);
        }
#pragma unroll
      for (int off = 1; off < 16; off <<= 1)
#pragma unroll
        for (int r = 0; r < 4; ++r)
          tmax[r] = fmaxf(tmax[r], __shfl_xor(tmax[r], off));
      float alpha[4];
#pragma unroll
      for (int r = 0; r < 4; ++r) {
        float mn = fmaxf(m_run[rb][r], tmax[r]);
        alpha[r] = (mn == NINF) ? 1.0f : __expf(m_run[rb][r] - mn);
        m_run[rb][r] = mn;
      }
      float psum[4] = { 0.f, 0.f, 0.f, 0.f };
#pragma unroll
      for (int nt = 0; nt < 2; ++nt)
#pragma unroll
        for (int r = 0; r < 4; ++r) {
          float sv = sc[nt][r];
          float p = (sv == NINF) ? 0.f : __expf(sv - m_run[rb][r]);
          sc[nt][r] = p;
          psum[r] += p;
        }
#pragma unroll
      for (int off = 1; off < 16; off <<= 1)
#pragma unroll
        for (int r = 0; r < 4; ++r)
          psum[r] += __shfl_xor(psum[r], off);
#pragma unroll
      for (int r = 0; r < 4; ++r) l_run[rb][r] = l_run[rb][r] * alpha[r] + psum[r];
#pragma unroll
      for (int n = 0; n < 8; ++n)
#pragma unroll
        for (int r = 0; r < 4; ++r) acc[rb][n][r] *= alpha[r];
#pragma unroll
      for (int nt = 0; nt < 2; ++nt)
#pragma unroll
        for (int r = 0; r < 4; ++r)
          Pb[w][rb * 16 + rg * 4 + r][nt * 16 + rr] = (f16)sc[nt][r];
    }

    // PV: A-fragments from Pb, B-fragments from swizzled Vs
    f16x8 pf0 = *reinterpret_cast<const f16x8*>(&Pb[w][rr][rg * 8]);
    f16x8 pf1 = *reinterpret_cast<const f16x8*>(&Pb[w][16 + rr][rg * 8]);
#pragma unroll
    for (int n = 0; n < 8; ++n) {
      int d = n * 16 + rr;
      f16x8 vf = *reinterpret_cast<const f16x8*>(
          (const char*)&Vs[bufs][0][0] + d * 64 + ((rg * 16) ^ ((d & 3) << 4)));
      acc[0][n] = __builtin_amdgcn_mfma_f32_16x16x32_f16(pf0, vf, acc[0][n], 0, 0, 0);
      acc[1][n] = __builtin_amdgcn_mfma_f32_16x16x32_f16(pf1, vf, acc[1][n], 0, 0, 0);
    }
    __syncthreads();   // prefetch complete (vmcnt drain) + all waves done with bufs
  }
#undef STAGE

  // epilogue: normalize, write ctx (bf16) strided into qkv k/v-part (stride 6144)
#pragma unroll
  for (int rb = 0; rb < 2; ++rb)
#pragma unroll
    for (int n = 0; n < 8; ++n)
#pragma unroll
      for (int r = 0; r < 4; ++r) {
        float o = acc[rb][n][r] / l_run[rb][r];
        int qi = qw + rb * 16 + rg * 4 + r;
        ctxh[(size_t)(b * S_ + qi) * 6144 + h * HD_ + n * 16 + rr] = f2bf(o);
      }
}

extern "C" void kernel_launch(void* const* d_in, const int* in_sizes, int n_in,
                              void* d_out, int out_size, void* d_ws, size_t ws_size,
                              hipStream_t stream) {
  const float* x    = (const float*)d_in[0];
  // d_in[1] = mask (recomputed analytically)
  const float* cosb = (const float*)d_in[2];
  const float* sinb = (const float*)d_in[3];
  const float* Wq   = (const float*)d_in[4];
  const float* Wk   = (const float*)d_in[5];
  const float* Wv   = (const float*)d_in[6];
  const float* Wo   = (const float*)d_in[7];
  const float* qsc  = (const float*)d_in[8];
  const float* ksc  = (const float*)d_in[9];
  float* out = (float*)d_out;

  char* ws = (char*)d_ws;
  const size_t MB = 1ull << 20;
  // [0,12)  wqkvT_h  -> after QKV gemm reused: kf [0,4), vb [4,8)
  // [12,24) wqkvT_l  -> reused: vtb [12,16)
  // [24,32) woT_h ; [32,40) woT_l
  // [40,88) qkv f32 (ctx bf16 lives strided in its k/v-part after attention)
  ushort_t* wqkvT_h = (ushort_t*)(ws + 0 * MB);
  ushort_t* wqkvT_l = (ushort_t*)(ws + 12 * MB);
  f16*      kf      = (f16*)(ws + 0 * MB);
  f16*      vb      = (f16*)(ws + 4 * MB);
  f16*      vtb     = (f16*)(ws + 12 * MB);
  ushort_t* woT_h   = (ushort_t*)(ws + 24 * MB);
  ushort_t* woT_l   = (ushort_t*)(ws + 32 * MB);
  float*    qkv     = (float*)(ws + 40 * MB);
  ushort_t* ctxh    = (ushort_t*)qkv + 4096;  // strided: row i at i*6144 + [0,2048)

  transpose_f32_split<<<dim3(64, 64), 256, 0, stream>>>(Wq, wqkvT_h, wqkvT_l, D_, 2048);
  transpose_f32_split<<<dim3(16, 64), 256, 0, stream>>>(Wk, wqkvT_h + (size_t)2048 * D_,
                                                        wqkvT_l + (size_t)2048 * D_, D_, 512);
  transpose_f32_split<<<dim3(16, 64), 256, 0, stream>>>(Wv, wqkvT_h + (size_t)2560 * D_,
                                                        wqkvT_l + (size_t)2560 * D_, D_, 512);
  transpose_f32_split<<<dim3(64, 64), 256, 0, stream>>>(Wo, woT_h, woT_l, D_, D_);
  gemm_split<0><<<dim3(NQKV_ / 128, M_ / 128), 256, 0, stream>>>(
      x, nullptr, (long)D_, wqkvT_h, wqkvT_l, qkv, M_, NQKV_, D_);
  norm_rope_kv<<<dim3(M_ * 8 / 4), 256, 0, stream>>>(qkv, cosb, sinb, ksc, kf, vb);
  transpose_bf16<<<dim3(HD_ / 32, S_ / 32, B_ * KVH_), 256, 0, stream>>>(
      (const ushort_t*)vb, (ushort_t*)vtb, S_, HD_);
  flash_attn<<<dim3(S_ / QBLK, H_, B_), 512, 0, stream>>>(qkv, cosb, sinb, qsc, kf, vtb, ctxh);
  gemm_split<1><<<dim3(D_ / 128, M_ / 128), 256, 0, stream>>>(
      nullptr, ctxh, 6144, woT_h, woT_l, out, M_, D_, D_);
}

// Round 4
// 277.755 us; speedup vs baseline: 2.2701x; 1.4301x over previous
//
#include <hip/hip_runtime.h>
#include <stdint.h>

#define B_ 2
#define S_ 2048
#define D_ 2048
#define H_ 16
#define KVH_ 4
#define HD_ 128
#define ROT_ 64
#define WINDOW_ 1024
#define EPS_ 1e-6f
#define M_ (B_ * S_)
#define NQKV_ 3072

#define QBLK 256
#define KVBLK 32

typedef unsigned short ushort_t;
typedef _Float16 f16;
typedef float f32x4 __attribute__((ext_vector_type(4)));
typedef f16 f16x8 __attribute__((ext_vector_type(8)));

#define NINF (-__builtin_inff())

// async global->LDS, 16B per lane. dst must be wave-uniform; HW adds lane*16.
__device__ __forceinline__ void gload16(const void* g, void* l) {
  __builtin_amdgcn_global_load_lds(
      (const __attribute__((address_space(1))) void*)g,
      (__attribute__((address_space(3))) void*)l, 16, 0, 0);
}

// ---------------- cast x (f32 -> f16), 8 elems/thread ----------------
__launch_bounds__(256, 4)
__global__ void cast_f32_f16(const float* __restrict__ src, f16* __restrict__ dst, int n8) {
  int i = blockIdx.x * 256 + threadIdx.x;
  if (i >= n8) return;
  float4 a = reinterpret_cast<const float4*>(src)[i * 2];
  float4 b = reinterpret_cast<const float4*>(src)[i * 2 + 1];
  f16x8 o = { (f16)a.x, (f16)a.y, (f16)a.z, (f16)a.w,
              (f16)b.x, (f16)b.y, (f16)b.z, (f16)b.w };
  reinterpret_cast<f16x8*>(dst)[i] = o;
}

// ---------------- transpose f32 [R][C] -> f16 [C][R] ----------------
__launch_bounds__(256, 4)
__global__ void transpose_f32_f16(const float* __restrict__ src, f16* __restrict__ dst,
                                  int R, int C) {
  __shared__ float tile[32][33];
  int c0 = blockIdx.x * 32, r0 = blockIdx.y * 32;
  int tx = threadIdx.x & 31, ty = threadIdx.x >> 5;
#pragma unroll
  for (int i = 0; i < 32; i += 8)
    tile[ty + i][tx] = src[(size_t)(r0 + ty + i) * C + c0 + tx];
  __syncthreads();
#pragma unroll
  for (int i = 0; i < 32; i += 8)
    dst[(size_t)(c0 + ty + i) * R + r0 + tx] = (f16)tile[tx][ty + i];
}

// ---------------- batched transpose 16-bit [R][C] -> [C][R] ----------------
__launch_bounds__(256, 4)
__global__ void transpose16(const ushort_t* __restrict__ src, ushort_t* __restrict__ dst,
                            int R, int C) {
  __shared__ ushort_t tile[32][33];
  size_t base = (size_t)blockIdx.z * R * C;
  src += base; dst += base;
  int c0 = blockIdx.x * 32, r0 = blockIdx.y * 32;
  int tx = threadIdx.x & 31, ty = threadIdx.x >> 5;
#pragma unroll
  for (int i = 0; i < 32; i += 8)
    tile[ty + i][tx] = src[(size_t)(r0 + ty + i) * C + c0 + tx];
  __syncthreads();
#pragma unroll
  for (int i = 0; i < 32; i += 8)
    dst[(size_t)(c0 + ty + i) * R + r0 + tx] = tile[tx][ty + i];
}

// ---------------- fp16 GEMM: C[M][N] f32 = A[M][K] @ Bt[N][K]^T ----------------
// m97 structure: 128x128 tile, BK=64, 4 waves (2x2 of 64x64), global_load_lds w16,
// XOR-swizzled LDS (linear dest, inverse-swizzled global source, swizzled ds_read).
__launch_bounds__(256, 2)
__global__ void gemm_f16(const f16* __restrict__ A, const f16* __restrict__ Bt,
                         float* __restrict__ C, int M, int N, int K) {
  __shared__ __attribute__((aligned(16))) f16 As[128][64];   // 16 KiB, rows 128 B
  __shared__ __attribute__((aligned(16))) f16 Bs[128][64];
  const int bm = blockIdx.y * 128, bn = blockIdx.x * 128;
  const int tid = threadIdx.x;
  const int lane = tid & 63, wid = tid >> 6;
  const int wm = (wid >> 1) * 64, wn = (wid & 1) * 64;
  const int rr = lane & 15, rg = lane >> 4;
  // staging: wave wid covers rows [wid*32, wid*32+32); lane -> row wid*32+g*8+(lane>>3),
  // 16B chunk (lane&7). Source col pre-swizzled: chunk ^ ((row&7)<<4); row&7 == lane>>3.
  const int sw = (((lane & 7) ^ (lane >> 3)) << 4);
  const int srw = lane >> 3;
  const char* Ab = (const char*)A + ((size_t)(bm + wid * 32 + srw) * K) * 2 + sw;
  const char* Bb = (const char*)Bt + ((size_t)(bn + wid * 32 + srw) * K) * 2 + sw;
  f32x4 acc[4][4] = {};
  for (int k0 = 0; k0 < K; k0 += 64) {
    __syncthreads();   // WAR: all waves done reading previous tile
#pragma unroll
    for (int g = 0; g < 4; ++g) {
      gload16(Ab + (size_t)(g * 8) * K * 2 + (size_t)k0 * 2,
              (char*)&As[0][0] + (wid * 32 + g * 8) * 128);
      gload16(Bb + (size_t)(g * 8) * K * 2 + (size_t)k0 * 2,
              (char*)&Bs[0][0] + (wid * 32 + g * 8) * 128);
    }
    __syncthreads();   // RAW: barrier drains vmcnt -> staged data visible
    f16x8 af[4][2], bf[4][2];
#pragma unroll
    for (int i = 0; i < 4; ++i)
#pragma unroll
      for (int kk = 0; kk < 2; ++kk) {
        af[i][kk] = *reinterpret_cast<const f16x8*>(
            (const char*)&As[0][0] + (wm + i * 16 + rr) * 128 +
            ((kk * 64 + rg * 16) ^ ((rr & 7) << 4)));
        bf[i][kk] = *reinterpret_cast<const f16x8*>(
            (const char*)&Bs[0][0] + (wn + i * 16 + rr) * 128 +
            ((kk * 64 + rg * 16) ^ ((rr & 7) << 4)));
      }
#pragma unroll
    for (int kk = 0; kk < 2; ++kk)
#pragma unroll
      for (int i = 0; i < 4; ++i)
#pragma unroll
        for (int j = 0; j < 4; ++j)
          acc[i][j] = __builtin_amdgcn_mfma_f32_16x16x32_f16(af[i][kk], bf[j][kk],
                                                             acc[i][j], 0, 0, 0);
  }
#pragma unroll
  for (int i = 0; i < 4; ++i)
#pragma unroll
    for (int j = 0; j < 4; ++j)
#pragma unroll
      for (int r = 0; r < 4; ++r)
        C[(size_t)(bm + wm + i * 16 + rg * 4 + r) * N + (bn + wn + j * 16 + rr)] = acc[i][j][r];
}

// ---------------- RMSNorm + RoPE for K and V, fp16 out ----------------
__launch_bounds__(256, 4)
__global__ void norm_rope_kv(const float* __restrict__ qkv, const float* __restrict__ cosb,
                             const float* __restrict__ sinb, const float* __restrict__ ksc,
                             f16* __restrict__ kf, f16* __restrict__ vb) {
  int gw = blockIdx.x * 4 + (threadIdx.x >> 6);
  int lane = threadIdx.x & 63;
  int row = gw >> 3, c = gw & 7;
  int b = row >> 11, s = row & (S_ - 1);
  int col = (c < 4) ? (2048 + c * 128) : (2560 + (c - 4) * 128);
  const float* src = qkv + (size_t)row * NQKV_ + col;
  float2 v = *reinterpret_cast<const float2*>(src + lane * 2);
  float ss = v.x * v.x + v.y * v.y;
#pragma unroll
  for (int off = 32; off; off >>= 1) ss += __shfl_xor(ss, off);
  float inv = rsqrtf(ss * (1.0f / HD_) + EPS_);
  float x0 = v.x * inv, x1 = v.y * inv;
  int d0 = lane * 2;
  f16* dst;
  size_t idx;
  if (c < 4) {  // k: (1+scale) then rope on dims [0,64)
    x0 *= (1.0f + ksc[d0]);
    x1 *= (1.0f + ksc[d0 + 1]);
    float y0 = __shfl_xor(x0, 16);
    float y1 = __shfl_xor(x1, 16);
    if (d0 < ROT_) {
      int dm = d0 & 31;
      float cs0 = cosb[s * 32 + dm],     sn0 = sinb[s * 32 + dm];
      float cs1 = cosb[s * 32 + dm + 1], sn1 = sinb[s * 32 + dm + 1];
      if (d0 < 32) { x0 = x0 * cs0 - y0 * sn0; x1 = x1 * cs1 - y1 * sn1; }
      else         { x0 = x0 * cs0 + y0 * sn0; x1 = x1 * cs1 + y1 * sn1; }
    }
    dst = kf; idx = ((size_t)((b * KVH_ + c) * S_ + s)) * HD_ + d0;
  } else {      // v: plain rmsnorm
    dst = vb; idx = ((size_t)((b * KVH_ + (c - 4)) * S_ + s)) * HD_ + d0;
  }
  f16 o[2] = { (f16)x0, (f16)x1 };
  unsigned int pk; __builtin_memcpy(&pk, o, 4);
  *reinterpret_cast<unsigned int*>(dst + idx) = pk;
}

// ---------------- flash attention: fp16 QK/PV, LDS-staged KV, double-buffered ----
// grid (S/256, H, B), 512 threads (8 waves), wave owns 32 q rows (2 rb of 16).
// K fp16 [S][128] staged swizzled ^((row&7)<<4); V^T fp16 [128][S] staged swizzled
// ^((d&3)<<4); both via global_load_lds w16 (linear dest, inv-swz source).
__launch_bounds__(512, 2)
__global__ void flash_attn(const float* __restrict__ qkv, const float* __restrict__ cosb,
                           const float* __restrict__ sinb, const float* __restrict__ qsc,
                           const f16* __restrict__ kfp, const f16* __restrict__ vt,
                           f16* __restrict__ ctxf) {
  __shared__ __attribute__((aligned(16))) f16 Ks[2][KVBLK][128];
  __shared__ __attribute__((aligned(16))) f16 Vs[2][128][KVBLK];
  __shared__ __attribute__((aligned(16))) f16 Pb[8][32][40];
  const int qtile = blockIdx.x, h = blockIdx.y, b = blockIdx.z;
  const int kvh = h >> 2;
  const int tid = threadIdx.x;
  const int lane = tid & 63, w = tid >> 6;
  const int rr = lane & 15, rg = lane >> 4;
  const int qBase = qtile * QBLK;
  const int qw = qBase + w * 32;
  const f16* Kh = kfp + (size_t)(b * KVH_ + kvh) * S_ * HD_;
  const f16* Vh = vt  + (size_t)(b * KVH_ + kvh) * HD_ * S_;

  // ---- q: load f32, rmsnorm, scale, rope, cvt fp16 (2 row-blocks) ----
  f16x8 qf[2][4];
#pragma unroll
  for (int rb = 0; rb < 2; ++rb) {
    const int srow = qw + rb * 16 + rr;
    const float* qrow = qkv + (size_t)(b * S_ + srow) * NQKV_ + h * HD_;
    float qv[4][8];
    float ssq = 0.f;
#pragma unroll
    for (int kk = 0; kk < 4; ++kk) {
      float4 u0 = *reinterpret_cast<const float4*>(qrow + kk * 32 + rg * 8);
      float4 u1 = *reinterpret_cast<const float4*>(qrow + kk * 32 + rg * 8 + 4);
      qv[kk][0] = u0.x; qv[kk][1] = u0.y; qv[kk][2] = u0.z; qv[kk][3] = u0.w;
      qv[kk][4] = u1.x; qv[kk][5] = u1.y; qv[kk][6] = u1.z; qv[kk][7] = u1.w;
#pragma unroll
      for (int j = 0; j < 8; ++j) ssq += qv[kk][j] * qv[kk][j];
    }
    ssq += __shfl_xor(ssq, 16);
    ssq += __shfl_xor(ssq, 32);
    float inv = rsqrtf(ssq * (1.0f / HD_) + EPS_);
#pragma unroll
    for (int kk = 0; kk < 4; ++kk)
#pragma unroll
      for (int j = 0; j < 8; ++j)
        qv[kk][j] *= inv * (1.0f + qsc[kk * 32 + rg * 8 + j]);
    {
      const float* cs = cosb + (size_t)srow * 32;
      const float* sn = sinb + (size_t)srow * 32;
#pragma unroll
      for (int j = 0; j < 8; ++j) {
        int d = rg * 8 + j;
        float c = cs[d], s = sn[d];
        float x0 = qv[0][j], x1 = qv[1][j];
        qv[0][j] = x0 * c - x1 * s;
        qv[1][j] = x1 * c + x0 * s;
      }
    }
#pragma unroll
    for (int kk = 0; kk < 4; ++kk)
#pragma unroll
      for (int j = 0; j < 8; ++j)
        qf[rb][kk][j] = (f16)qv[kk][j];
  }

  f32x4 acc[2][8] = {};
  float m_run[2][4], l_run[2][4];
#pragma unroll
  for (int rb = 0; rb < 2; ++rb)
#pragma unroll
    for (int r = 0; r < 4; ++r) { m_run[rb][r] = NINF; l_run[rb][r] = 0.f; }

  int kvStart = qBase - (WINDOW_ - 1);
  if (kvStart < 0) kvStart = 0;
  kvStart &= ~(KVBLK - 1);
  const int ntile = (qBase + QBLK - kvStart) / KVBLK;

  // stage K rows rt = w*4 + lane/16, 16B chunk (lane&15); V rows d = w*16 + lane/4.
  const int k_rt = w * 4 + (lane >> 4);
  const int k_cb = (lane & 15) * 16;
  const int k_src_off = (k_cb ^ ((k_rt & 7) << 4));
  const int v_d = w * 16 + (lane >> 2);
  const int v_cb = (lane & 3) * 16;
  const size_t v_src_base = (size_t)v_d * (S_ * 2) + (v_cb ^ ((v_d & 3) << 4));

#define STAGE(bufs, key0)                                                            \
  do {                                                                               \
    gload16((const char*)Kh + (size_t)((key0) + k_rt) * 256 + k_src_off,             \
            (f16*)&Ks[bufs][0][0] + w * 512);                                        \
    gload16((const char*)Vh + v_src_base + (size_t)(key0) * 2,                       \
            (f16*)&Vs[bufs][0][0] + w * 512);                                        \
  } while (0)

  STAGE(0, kvStart);
  __syncthreads();

  for (int t = 0; t < ntile; ++t) {
    const int key0 = kvStart + t * KVBLK;
    const int bufs = t & 1;
    if (t + 1 < ntile) STAGE(bufs ^ 1, key0 + KVBLK);

    // K fragments (shared across both row-blocks)
    f16x8 kfr[2][4];
#pragma unroll
    for (int nt = 0; nt < 2; ++nt)
#pragma unroll
      for (int kk = 0; kk < 4; ++kk) {
        int rt = nt * 16 + rr;
        kfr[nt][kk] = *reinterpret_cast<const f16x8*>(
            (const char*)&Ks[bufs][0][0] + rt * 256 + ((kk * 64 + rg * 16) ^ ((rt & 7) << 4)));
      }

#pragma unroll
    for (int rb = 0; rb < 2; ++rb) {
      f32x4 sc[2];
#pragma unroll
      for (int nt = 0; nt < 2; ++nt) {
        f32x4 s = {};
#pragma unroll
        for (int kk = 0; kk < 4; ++kk)
          s = __builtin_amdgcn_mfma_f32_16x16x32_f16(qf[rb][kk], kfr[nt][kk], s, 0, 0, 0);
        sc[nt] = s;
      }
      float tmax[4] = { NINF, NINF, NINF, NINF };
#pragma unroll
      for (int nt = 0; nt < 2; ++nt)
#pragma unroll
        for (int r = 0; r < 4; ++r) {
          int qi = qw + rb * 16 + rg * 4 + r;
          int kj = key0 + nt * 16 + rr;
          bool valid = (kj <= qi) && (qi - kj < WINDOW_);
          float sv = valid ? sc[nt][r] : NINF;
          sc[nt][r] = sv;
          tmax[r] = fmaxf(tmax[r], sv);
        }
#pragma unroll
      for (int off = 1; off < 16; off <<= 1)
#pragma unroll
        for (int r = 0; r < 4; ++r)
          tmax[r] = fmaxf(tmax[r], __shfl_xor(tmax[r], off));
      float alpha[4];
#pragma unroll
      for (int r = 0; r < 4; ++r) {
        float mn = fmaxf(m_run[rb][r], tmax[r]);
        alpha[r] = (mn == NINF) ? 1.0f : __expf(m_run[rb][r] - mn);
        m_run[rb][r] = mn;
      }
      float psum[4] = { 0.f, 0.f, 0.f, 0.f };
#pragma unroll
      for (int nt = 0; nt < 2; ++nt)
#pragma unroll
        for (int r = 0; r < 4; ++r) {
          float sv = sc[nt][r];
          float p = (sv == NINF) ? 0.f : __expf(sv - m_run[rb][r]);
          sc[nt][r] = p;
          psum[r] += p;
        }
#pragma unroll
      for (int off = 1; off < 16; off <<= 1)
#pragma unroll
        for (int r = 0; r < 4; ++r)
          psum[r] += __shfl_xor(psum[r], off);
#pragma unroll
      for (int r = 0; r < 4; ++r) l_run[rb][r] = l_run[rb][r] * alpha[r] + psum[r];
#pragma unroll
      for (int n = 0; n < 8; ++n)
#pragma unroll
        for (int r = 0; r < 4; ++r) acc[rb][n][r] *= alpha[r];
#pragma unroll
      for (int nt = 0; nt < 2; ++nt)
#pragma unroll
        for (int r = 0; r < 4; ++r)
          Pb[w][rb * 16 + rg * 4 + r][nt * 16 + rr] = (f16)sc[nt][r];
    }

    // PV: A-fragments from Pb, B-fragments from swizzled Vs
    f16x8 pf0 = *reinterpret_cast<const f16x8*>(&Pb[w][rr][rg * 8]);
    f16x8 pf1 = *reinterpret_cast<const f16x8*>(&Pb[w][16 + rr][rg * 8]);
#pragma unroll
    for (int n = 0; n < 8; ++n) {
      int d = n * 16 + rr;
      f16x8 vf = *reinterpret_cast<const f16x8*>(
          (const char*)&Vs[bufs][0][0] + d * 64 + ((rg * 16) ^ ((d & 3) << 4)));
      acc[0][n] = __builtin_amdgcn_mfma_f32_16x16x32_f16(pf0, vf, acc[0][n], 0, 0, 0);
      acc[1][n] = __builtin_amdgcn_mfma_f32_16x16x32_f16(pf1, vf, acc[1][n], 0, 0, 0);
    }
    __syncthreads();   // prefetch complete (vmcnt drain) + all waves done with bufs
  }
#undef STAGE

  // epilogue: normalize, write ctx fp16 contiguous [M][2048]
#pragma unroll
  for (int rb = 0; rb < 2; ++rb)
#pragma unroll
    for (int n = 0; n < 8; ++n)
#pragma unroll
      for (int r = 0; r < 4; ++r) {
        float o = acc[rb][n][r] / l_run[rb][r];
        int qi = qw + rb * 16 + rg * 4 + r;
        ctxf[(size_t)(b * S_ + qi) * D_ + h * HD_ + n * 16 + rr] = (f16)o;
      }
}

extern "C" void kernel_launch(void* const* d_in, const int* in_sizes, int n_in,
                              void* d_out, int out_size, void* d_ws, size_t ws_size,
                              hipStream_t stream) {
  const float* x    = (const float*)d_in[0];
  // d_in[1] = mask (recomputed analytically)
  const float* cosb = (const float*)d_in[2];
  const float* sinb = (const float*)d_in[3];
  const float* Wq   = (const float*)d_in[4];
  const float* Wk   = (const float*)d_in[5];
  const float* Wv   = (const float*)d_in[6];
  const float* Wo   = (const float*)d_in[7];
  const float* qsc  = (const float*)d_in[8];
  const float* ksc  = (const float*)d_in[9];
  float* out = (float*)d_out;

  char* ws = (char*)d_ws;
  const size_t MB = 1ull << 20;
  // [0,16)  xh fp16         -> after gemm0 reused: ctxf fp16
  // [16,28) wqkvT fp16      -> after gemm0 reused: kf[16,20) vb[20,24) vtb[24,28)
  // [28,36) woT fp16
  // [36,84) qkv f32
  f16* xh    = (f16*)(ws + 0 * MB);
  f16* ctxf  = (f16*)(ws + 0 * MB);
  f16* wqkvT = (f16*)(ws + 16 * MB);
  f16* kf    = (f16*)(ws + 16 * MB);
  f16* vb    = (f16*)(ws + 20 * MB);
  f16* vtb   = (f16*)(ws + 24 * MB);
  f16* woT   = (f16*)(ws + 28 * MB);
  float* qkv = (float*)(ws + 36 * MB);

  cast_f32_f16<<<dim3(M_ * D_ / 8 / 256), 256, 0, stream>>>(x, xh, M_ * D_ / 8);
  transpose_f32_f16<<<dim3(64, 64), 256, 0, stream>>>(Wq, wqkvT, D_, 2048);
  transpose_f32_f16<<<dim3(16, 64), 256, 0, stream>>>(Wk, wqkvT + (size_t)2048 * D_, D_, 512);
  transpose_f32_f16<<<dim3(16, 64), 256, 0, stream>>>(Wv, wqkvT + (size_t)2560 * D_, D_, 512);
  transpose_f32_f16<<<dim3(64, 64), 256, 0, stream>>>(Wo, woT, D_, D_);
  gemm_f16<<<dim3(NQKV_ / 128, M_ / 128), 256, 0, stream>>>(xh, wqkvT, qkv, M_, NQKV_, D_);
  norm_rope_kv<<<dim3(M_ * 8 / 4), 256, 0, stream>>>(qkv, cosb, sinb, ksc, kf, vb);
  transpose16<<<dim3(HD_ / 32, S_ / 32, B_ * KVH_), 256, 0, stream>>>(
      (const ushort_t*)vb, (ushort_t*)vtb, S_, HD_);
  flash_attn<<<dim3(S_ / QBLK, H_, B_), 512, 0, stream>>>(qkv, cosb, sinb, qsc, kf, vtb, ctxf);
  gemm_f16<<<dim3(D_ / 128, M_ / 128), 256, 0, stream>>>(ctxf, woT, out, M_, D_, D_);
}

// Round 5
// 219.506 us; speedup vs baseline: 2.8725x; 1.2654x over previous
//
#include <hip/hip_runtime.h>
#include <stdint.h>

#define B_ 2
#define S_ 2048
#define D_ 2048
#define H_ 16
#define KVH_ 4
#define HD_ 128
#define ROT_ 64
#define WINDOW_ 1024
#define EPS_ 1e-6f
#define M_ (B_ * S_)
#define NQKV_ 3072

#define QBLK 128
#define KVBLK 64

typedef unsigned short ushort_t;
typedef _Float16 f16;
typedef float f32x4 __attribute__((ext_vector_type(4)));
typedef f16 f16x8 __attribute__((ext_vector_type(8)));

#define NINF (-__builtin_inff())

// async global->LDS, 16B per lane. dst must be wave-uniform; HW adds lane*16.
__device__ __forceinline__ void gload16(const void* g, void* l) {
  __builtin_amdgcn_global_load_lds(
      (const __attribute__((address_space(1))) void*)g,
      (__attribute__((address_space(3))) void*)l, 16, 0, 0);
}

// ---------------- cast x (f32 -> f16), 8 elems/thread ----------------
__launch_bounds__(256, 4)
__global__ void cast_f32_f16(const float* __restrict__ src, f16* __restrict__ dst, int n8) {
  int i = blockIdx.x * 256 + threadIdx.x;
  if (i >= n8) return;
  float4 a = reinterpret_cast<const float4*>(src)[i * 2];
  float4 b = reinterpret_cast<const float4*>(src)[i * 2 + 1];
  f16x8 o = { (f16)a.x, (f16)a.y, (f16)a.z, (f16)a.w,
              (f16)b.x, (f16)b.y, (f16)b.z, (f16)b.w };
  reinterpret_cast<f16x8*>(dst)[i] = o;
}

// ---------------- transpose f32 [R][C] -> f16 [C][R] ----------------
__launch_bounds__(256, 4)
__global__ void transpose_f32_f16(const float* __restrict__ src, f16* __restrict__ dst,
                                  int R, int C) {
  __shared__ float tile[32][33];
  int c0 = blockIdx.x * 32, r0 = blockIdx.y * 32;
  int tx = threadIdx.x & 31, ty = threadIdx.x >> 5;
#pragma unroll
  for (int i = 0; i < 32; i += 8)
    tile[ty + i][tx] = src[(size_t)(r0 + ty + i) * C + c0 + tx];
  __syncthreads();
#pragma unroll
  for (int i = 0; i < 32; i += 8)
    dst[(size_t)(c0 + ty + i) * R + r0 + tx] = (f16)tile[tx][ty + i];
}

// ---------------- batched transpose 16-bit [R][C] -> [C][R] ----------------
__launch_bounds__(256, 4)
__global__ void transpose16(const ushort_t* __restrict__ src, ushort_t* __restrict__ dst,
                            int R, int C) {
  __shared__ ushort_t tile[32][33];
  size_t base = (size_t)blockIdx.z * R * C;
  src += base; dst += base;
  int c0 = blockIdx.x * 32, r0 = blockIdx.y * 32;
  int tx = threadIdx.x & 31, ty = threadIdx.x >> 5;
#pragma unroll
  for (int i = 0; i < 32; i += 8)
    tile[ty + i][tx] = src[(size_t)(r0 + ty + i) * C + c0 + tx];
  __syncthreads();
#pragma unroll
  for (int i = 0; i < 32; i += 8)
    dst[(size_t)(c0 + ty + i) * R + r0 + tx] = tile[tx][ty + i];
}

// ---------------- fp16 GEMM: C[M][N] f32 = A[M][K] @ Bt[N][K]^T ----------------
// m97 structure + XCD-aware block swizzle (grid blocks % 8 == 0 required).
__launch_bounds__(256, 2)
__global__ void gemm_f16(const f16* __restrict__ A, const f16* __restrict__ Bt,
                         float* __restrict__ C, int M, int N, int K) {
  __shared__ __attribute__((aligned(16))) f16 As[128][64];
  __shared__ __attribute__((aligned(16))) f16 Bs[128][64];
  // XCD swizzle: consecutive swizzled ids share A-panels within one XCD
  const int gx = gridDim.x;
  const int nwg = gx * gridDim.y;
  const int flat = blockIdx.y * gx + blockIdx.x;
  const int q8 = nwg >> 3;
  const int id2 = (flat & 7) * q8 + (flat >> 3);
  const int bm = (id2 / gx) * 128, bn = (id2 % gx) * 128;
  const int tid = threadIdx.x;
  const int lane = tid & 63, wid = tid >> 6;
  const int wm = (wid >> 1) * 64, wn = (wid & 1) * 64;
  const int rr = lane & 15, rg = lane >> 4;
  const int sw = (((lane & 7) ^ (lane >> 3)) << 4);
  const int srw = lane >> 3;
  const char* Ab = (const char*)A + ((size_t)(bm + wid * 32 + srw) * K) * 2 + sw;
  const char* Bb = (const char*)Bt + ((size_t)(bn + wid * 32 + srw) * K) * 2 + sw;
  f32x4 acc[4][4] = {};
  for (int k0 = 0; k0 < K; k0 += 64) {
    __syncthreads();   // WAR: all waves done reading previous tile
#pragma unroll
    for (int g = 0; g < 4; ++g) {
      gload16(Ab + (size_t)(g * 8) * K * 2 + (size_t)k0 * 2,
              (char*)&As[0][0] + (wid * 32 + g * 8) * 128);
      gload16(Bb + (size_t)(g * 8) * K * 2 + (size_t)k0 * 2,
              (char*)&Bs[0][0] + (wid * 32 + g * 8) * 128);
    }
    __syncthreads();   // RAW: barrier drains vmcnt -> staged data visible
    f16x8 af[4][2], bf[4][2];
#pragma unroll
    for (int i = 0; i < 4; ++i)
#pragma unroll
      for (int kk = 0; kk < 2; ++kk) {
        af[i][kk] = *reinterpret_cast<const f16x8*>(
            (const char*)&As[0][0] + (wm + i * 16 + rr) * 128 +
            ((kk * 64 + rg * 16) ^ ((rr & 7) << 4)));
        bf[i][kk] = *reinterpret_cast<const f16x8*>(
            (const char*)&Bs[0][0] + (wn + i * 16 + rr) * 128 +
            ((kk * 64 + rg * 16) ^ ((rr & 7) << 4)));
      }
#pragma unroll
    for (int kk = 0; kk < 2; ++kk)
#pragma unroll
      for (int i = 0; i < 4; ++i)
#pragma unroll
        for (int j = 0; j < 4; ++j)
          acc[i][j] = __builtin_amdgcn_mfma_f32_16x16x32_f16(af[i][kk], bf[j][kk],
                                                             acc[i][j], 0, 0, 0);
  }
#pragma unroll
  for (int i = 0; i < 4; ++i)
#pragma unroll
    for (int j = 0; j < 4; ++j)
#pragma unroll
      for (int r = 0; r < 4; ++r)
        C[(size_t)(bm + wm + i * 16 + rg * 4 + r) * N + (bn + wn + j * 16 + rr)] = acc[i][j][r];
}

// ---------------- RMSNorm + RoPE for K and V, fp16 out ----------------
__launch_bounds__(256, 4)
__global__ void norm_rope_kv(const float* __restrict__ qkv, const float* __restrict__ cosb,
                             const float* __restrict__ sinb, const float* __restrict__ ksc,
                             f16* __restrict__ kf, f16* __restrict__ vb) {
  int gw = blockIdx.x * 4 + (threadIdx.x >> 6);
  int lane = threadIdx.x & 63;
  int row = gw >> 3, c = gw & 7;
  int b = row >> 11, s = row & (S_ - 1);
  int col = (c < 4) ? (2048 + c * 128) : (2560 + (c - 4) * 128);
  const float* src = qkv + (size_t)row * NQKV_ + col;
  float2 v = *reinterpret_cast<const float2*>(src + lane * 2);
  float ss = v.x * v.x + v.y * v.y;
#pragma unroll
  for (int off = 32; off; off >>= 1) ss += __shfl_xor(ss, off);
  float inv = rsqrtf(ss * (1.0f / HD_) + EPS_);
  float x0 = v.x * inv, x1 = v.y * inv;
  int d0 = lane * 2;
  f16* dst;
  size_t idx;
  if (c < 4) {  // k: (1+scale) then rope on dims [0,64)
    x0 *= (1.0f + ksc[d0]);
    x1 *= (1.0f + ksc[d0 + 1]);
    float y0 = __shfl_xor(x0, 16);
    float y1 = __shfl_xor(x1, 16);
    if (d0 < ROT_) {
      int dm = d0 & 31;
      float cs0 = cosb[s * 32 + dm],     sn0 = sinb[s * 32 + dm];
      float cs1 = cosb[s * 32 + dm + 1], sn1 = sinb[s * 32 + dm + 1];
      if (d0 < 32) { x0 = x0 * cs0 - y0 * sn0; x1 = x1 * cs1 - y1 * sn1; }
      else         { x0 = x0 * cs0 + y0 * sn0; x1 = x1 * cs1 + y1 * sn1; }
    }
    dst = kf; idx = ((size_t)((b * KVH_ + c) * S_ + s)) * HD_ + d0;
  } else {      // v: plain rmsnorm
    dst = vb; idx = ((size_t)((b * KVH_ + (c - 4)) * S_ + s)) * HD_ + d0;
  }
  f16 o[2] = { (f16)x0, (f16)x1 };
  unsigned int pk; __builtin_memcpy(&pk, o, 4);
  *reinterpret_cast<unsigned int*>(dst + idx) = pk;
}

// ---------------- flash attention v4 ----------------
// 1D grid 512 blocks (XCD-swizzled: blocks sharing (b,kvh) -> same XCD), 512 thr
// (8 waves), QBLK=128 (16 q-rows/wave), KVBLK=64. K [S][128] and V^T [128][S]
// staged via global_load_lds w16, XOR-swizzled ^((row&7)<<4). Row-sum l computed
// by MFMA against all-ones B-fragment (no psum shuffle chain).
__launch_bounds__(512, 4)
__global__ void flash_attn(const float* __restrict__ qkv, const float* __restrict__ cosb,
                           const float* __restrict__ sinb, const float* __restrict__ qsc,
                           const f16* __restrict__ kfp, const f16* __restrict__ vt,
                           f16* __restrict__ ctxf) {
  __shared__ __attribute__((aligned(16))) f16 Ks[2][KVBLK][128];   // 32 KB
  __shared__ __attribute__((aligned(16))) f16 Vs[2][128][KVBLK];   // 32 KB
  __shared__ __attribute__((aligned(16))) f16 Pb[8][16][40];       // 10.2 KB
  // decode XCD-swizzled block id: g = (b,kvh) group -> one XCD per group
  const int id = blockIdx.x;
  const int g8 = id & 7, wvb = id >> 3;
  const int b = g8 >> 2, kvh = g8 & 3;
  const int h = kvh * 4 + (wvb >> 4);
  const int qtile = wvb & 15;
  const int tid = threadIdx.x;
  const int lane = tid & 63, w = tid >> 6;
  const int rr = lane & 15, rg = lane >> 4;
  const int qBase = qtile * QBLK;
  const int qw = qBase + w * 16;
  const f16* Kh = kfp + (size_t)(b * KVH_ + kvh) * S_ * HD_;
  const f16* Vh = vt  + (size_t)(b * KVH_ + kvh) * HD_ * S_;

  // ---- q: load f32, rmsnorm, scale, rope, cvt fp16 (16 rows/wave) ----
  f16x8 qf[4];
  {
    const int srow = qw + rr;
    const float* qrow = qkv + (size_t)(b * S_ + srow) * NQKV_ + h * HD_;
    float qv[4][8];
    float ssq = 0.f;
#pragma unroll
    for (int kk = 0; kk < 4; ++kk) {
      float4 u0 = *reinterpret_cast<const float4*>(qrow + kk * 32 + rg * 8);
      float4 u1 = *reinterpret_cast<const float4*>(qrow + kk * 32 + rg * 8 + 4);
      qv[kk][0] = u0.x; qv[kk][1] = u0.y; qv[kk][2] = u0.z; qv[kk][3] = u0.w;
      qv[kk][4] = u1.x; qv[kk][5] = u1.y; qv[kk][6] = u1.z; qv[kk][7] = u1.w;
#pragma unroll
      for (int j = 0; j < 8; ++j) ssq += qv[kk][j] * qv[kk][j];
    }
    ssq += __shfl_xor(ssq, 16);
    ssq += __shfl_xor(ssq, 32);
    float inv = rsqrtf(ssq * (1.0f / HD_) + EPS_);
#pragma unroll
    for (int kk = 0; kk < 4; ++kk)
#pragma unroll
      for (int j = 0; j < 8; ++j)
        qv[kk][j] *= inv * (1.0f + qsc[kk * 32 + rg * 8 + j]);
    const float* cs = cosb + (size_t)srow * 32;
    const float* sn = sinb + (size_t)srow * 32;
#pragma unroll
    for (int j = 0; j < 8; ++j) {
      int d = rg * 8 + j;
      float c = cs[d], s = sn[d];
      float x0 = qv[0][j], x1 = qv[1][j];
      qv[0][j] = x0 * c - x1 * s;
      qv[1][j] = x1 * c + x0 * s;
    }
#pragma unroll
    for (int kk = 0; kk < 4; ++kk)
#pragma unroll
      for (int j = 0; j < 8; ++j)
        qf[kk][j] = (f16)qv[kk][j];
  }

  f32x4 acc[8] = {};
  f32x4 accl = {};
  float m_run[4];
#pragma unroll
  for (int r = 0; r < 4; ++r) m_run[r] = NINF;
  const f16x8 ones = { (f16)1, (f16)1, (f16)1, (f16)1, (f16)1, (f16)1, (f16)1, (f16)1 };

  int kvStart = qBase - (WINDOW_ - 1);
  if (kvStart < 0) kvStart = 0;
  kvStart &= ~(KVBLK - 1);
  const int ntile = (qBase + QBLK - kvStart) / KVBLK;

  // staging lane mapping
  const int k_r0 = lane >> 4;          // row within 4-row chunk
  const int k_cb = (lane & 15) * 16;   // 16B chunk within 256B row
  const int v_r0 = lane >> 3;          // row within 8-row chunk
  const int v_cb = (lane & 7) * 16;    // 16B chunk within 128B row

#define STAGE(bufs, key0_)                                                           \
  do {                                                                               \
    _Pragma("unroll")                                                                \
    for (int gg = 0; gg < 2; ++gg) {                                                 \
      int krow = gg * 4 + k_r0;                                                      \
      gload16((const char*)Kh + (size_t)((key0_) + w * 8 + krow) * 256 +             \
                  (k_cb ^ ((krow & 7) << 4)),                                        \
              (char*)&Ks[bufs][0][0] + (w * 8 + gg * 4) * 256);                      \
      int vrow = gg * 8 + v_r0;                                                      \
      gload16((const char*)Vh + (size_t)(w * 16 + vrow) * (S_ * 2) +                 \
                  (size_t)(key0_) * 2 + (v_cb ^ ((vrow & 7) << 4)),                  \
              (char*)&Vs[bufs][0][0] + (w * 16 + gg * 8) * 128);                     \
    }                                                                                \
  } while (0)

  STAGE(0, kvStart);
  __syncthreads();

  for (int t = 0; t < ntile; ++t) {
    const int key0 = kvStart + t * KVBLK;
    const int buf = t & 1;
    if (t + 1 < ntile) STAGE(buf ^ 1, key0 + KVBLK);

    // ---- QK^T: 4 nt x 4 kk MFMA ----
    f32x4 sc[4];
#pragma unroll
    for (int nt = 0; nt < 4; ++nt) {
      const int rt = nt * 16 + rr;
      const char* kbase = (const char*)&Ks[buf][0][0] + rt * 256;
      const int swz = (rt & 7) << 4;
      f32x4 s = {};
#pragma unroll
      for (int kk = 0; kk < 4; ++kk) {
        f16x8 kfr = *reinterpret_cast<const f16x8*>(kbase + ((kk * 64 + rg * 16) ^ swz));
        s = __builtin_amdgcn_mfma_f32_16x16x32_f16(qf[kk], kfr, s, 0, 0, 0);
      }
      sc[nt] = s;
    }

    // ---- mask (skipped for interior tiles) ----
    const bool interior = (key0 + 63 <= qw) && (key0 >= qw - 1008);
    if (!interior) {
#pragma unroll
      for (int nt = 0; nt < 4; ++nt)
#pragma unroll
        for (int r = 0; r < 4; ++r) {
          int qi = qw + rg * 4 + r;
          int kj = key0 + nt * 16 + rr;
          bool valid = (kj <= qi) && (qi - kj < WINDOW_);
          if (!valid) sc[nt][r] = NINF;
        }
    }

    // ---- row max (4-step shuffle within 16-lane groups) ----
    float tmax[4];
#pragma unroll
    for (int r = 0; r < 4; ++r)
      tmax[r] = fmaxf(fmaxf(sc[0][r], sc[1][r]), fmaxf(sc[2][r], sc[3][r]));
#pragma unroll
    for (int off = 1; off < 16; off <<= 1)
#pragma unroll
      for (int r = 0; r < 4; ++r)
        tmax[r] = fmaxf(tmax[r], __shfl_xor(tmax[r], off));

    float alpha[4], msafe[4];
#pragma unroll
    for (int r = 0; r < 4; ++r) {
      float mn = fmaxf(m_run[r], tmax[r]);
      msafe[r] = (mn == NINF) ? 0.f : mn;
      alpha[r] = (m_run[r] == NINF) ? 0.f : __expf(m_run[r] - mn);
      m_run[r] = mn;
    }
    // exp (exp(-inf - msafe) = 0, no NaN since msafe finite)
#pragma unroll
    for (int nt = 0; nt < 4; ++nt)
#pragma unroll
      for (int r = 0; r < 4; ++r)
        sc[nt][r] = __expf(sc[nt][r] - msafe[r]);
    // rescale accumulators
#pragma unroll
    for (int n = 0; n < 8; ++n)
#pragma unroll
      for (int r = 0; r < 4; ++r) acc[n][r] *= alpha[r];
#pragma unroll
    for (int r = 0; r < 4; ++r) accl[r] *= alpha[r];

    // ---- P -> LDS (two passes through 32-col buffer), PV MFMA ----
#pragma unroll
    for (int nt = 0; nt < 2; ++nt)
#pragma unroll
      for (int r = 0; r < 4; ++r)
        Pb[w][rg * 4 + r][nt * 16 + rr] = (f16)sc[nt][r];
    f16x8 pf0 = *reinterpret_cast<const f16x8*>(&Pb[w][rr][rg * 8]);
#pragma unroll
    for (int nt = 0; nt < 2; ++nt)
#pragma unroll
      for (int r = 0; r < 4; ++r)
        Pb[w][rg * 4 + r][nt * 16 + rr] = (f16)sc[2 + nt][r];
    f16x8 pf1 = *reinterpret_cast<const f16x8*>(&Pb[w][rr][rg * 8]);

    __builtin_amdgcn_s_setprio(1);
#pragma unroll
    for (int n = 0; n < 8; ++n) {
      const int d = n * 16 + rr;
      const char* vbase = (const char*)&Vs[buf][0][0] + d * 128;
      const int swz = (d & 7) << 4;
      f16x8 vf0 = *reinterpret_cast<const f16x8*>(vbase + ((rg * 16) ^ swz));
      f16x8 vf1 = *reinterpret_cast<const f16x8*>(vbase + ((64 + rg * 16) ^ swz));
      acc[n] = __builtin_amdgcn_mfma_f32_16x16x32_f16(pf0, vf0, acc[n], 0, 0, 0);
      acc[n] = __builtin_amdgcn_mfma_f32_16x16x32_f16(pf1, vf1, acc[n], 0, 0, 0);
    }
    accl = __builtin_amdgcn_mfma_f32_16x16x32_f16(pf0, ones, accl, 0, 0, 0);
    accl = __builtin_amdgcn_mfma_f32_16x16x32_f16(pf1, ones, accl, 0, 0, 0);
    __builtin_amdgcn_s_setprio(0);

    __syncthreads();   // drains prefetch vmcnt + all waves done with buf
  }
#undef STAGE

  // epilogue: normalize, write ctx fp16 contiguous [M][2048]
#pragma unroll
  for (int n = 0; n < 8; ++n)
#pragma unroll
    for (int r = 0; r < 4; ++r) {
      float o = acc[n][r] / accl[r];
      int qi = qw + rg * 4 + r;
      ctxf[(size_t)(b * S_ + qi) * D_ + h * HD_ + n * 16 + rr] = (f16)o;
    }
}

extern "C" void kernel_launch(void* const* d_in, const int* in_sizes, int n_in,
                              void* d_out, int out_size, void* d_ws, size_t ws_size,
                              hipStream_t stream) {
  const float* x    = (const float*)d_in[0];
  // d_in[1] = mask (recomputed analytically)
  const float* cosb = (const float*)d_in[2];
  const float* sinb = (const float*)d_in[3];
  const float* Wq   = (const float*)d_in[4];
  const float* Wk   = (const float*)d_in[5];
  const float* Wv   = (const float*)d_in[6];
  const float* Wo   = (const float*)d_in[7];
  const float* qsc  = (const float*)d_in[8];
  const float* ksc  = (const float*)d_in[9];
  float* out = (float*)d_out;

  char* ws = (char*)d_ws;
  const size_t MB = 1ull << 20;
  // [0,16)  xh fp16         -> after gemm0 reused: ctxf fp16
  // [16,28) wqkvT fp16      -> after gemm0 reused: kf[16,20) vb[20,24) vtb[24,28)
  // [28,36) woT fp16
  // [36,84) qkv f32
  f16* xh    = (f16*)(ws + 0 * MB);
  f16* ctxf  = (f16*)(ws + 0 * MB);
  f16* wqkvT = (f16*)(ws + 16 * MB);
  f16* kf    = (f16*)(ws + 16 * MB);
  f16* vb    = (f16*)(ws + 20 * MB);
  f16* vtb   = (f16*)(ws + 24 * MB);
  f16* woT   = (f16*)(ws + 28 * MB);
  float* qkv = (float*)(ws + 36 * MB);

  cast_f32_f16<<<dim3(M_ * D_ / 8 / 256), 256, 0, stream>>>(x, xh, M_ * D_ / 8);
  transpose_f32_f16<<<dim3(64, 64), 256, 0, stream>>>(Wq, wqkvT, D_, 2048);
  transpose_f32_f16<<<dim3(16, 64), 256, 0, stream>>>(Wk, wqkvT + (size_t)2048 * D_, D_, 512);
  transpose_f32_f16<<<dim3(16, 64), 256, 0, stream>>>(Wv, wqkvT + (size_t)2560 * D_, D_, 512);
  transpose_f32_f16<<<dim3(64, 64), 256, 0, stream>>>(Wo, woT, D_, D_);
  gemm_f16<<<dim3(NQKV_ / 128, M_ / 128), 256, 0, stream>>>(xh, wqkvT, qkv, M_, NQKV_, D_);
  norm_rope_kv<<<dim3(M_ * 8 / 4), 256, 0, stream>>>(qkv, cosb, sinb, ksc, kf, vb);
  transpose16<<<dim3(HD_ / 32, S_ / 32, B_ * KVH_), 256, 0, stream>>>(
      (const ushort_t*)vb, (ushort_t*)vtb, S_, HD_);
  flash_attn<<<dim3((S_ / QBLK) * H_ * B_), 512, 0, stream>>>(
      qkv, cosb, sinb, qsc, kf, vtb, ctxf);
  gemm_f16<<<dim3(D_ / 128, M_ / 128), 256, 0, stream>>>(ctxf, woT, out, M_, D_, D_);
}